// Round 12
// baseline (2621.942 us; speedup 1.0000x reference)
//
#include <hip/hip_runtime.h>
#include <hip/hip_fp16.h>
#include <stdint.h>

#define S_LEN 1024
#define BATCH 64
#define HID   512
#define VOC   256

typedef _Float16 h2v __attribute__((ext_vector_type(2)));
typedef _Float16 h8v __attribute__((ext_vector_type(8)));
typedef float    f4v __attribute__((ext_vector_type(4)));

__device__ __forceinline__ float fdot2f(uint32_t w, uint32_t h, float c) {
#if __has_builtin(__builtin_amdgcn_fdot2)
  return __builtin_amdgcn_fdot2(__builtin_bit_cast(h2v, w),
                                __builtin_bit_cast(h2v, h), c, false);
#else
  h2v a = __builtin_bit_cast(h2v, w);
  h2v b = __builtin_bit_cast(h2v, h);
  return c + (float)a.x * (float)b.x + (float)a.y * (float)b.y;
#endif
}

// ---------------- prep kernels ----------------
__global__ void prep_whh(const float* __restrict__ whh, uint32_t* __restrict__ wp) {
  int idx = blockIdx.x * blockDim.x + threadIdx.x;   // 131072
  int k2 = idx >> 9;
  int n  = idx & 511;
  float a = whh[(2 * k2) * HID + n];
  float b = whh[(2 * k2 + 1) * HID + n];
  h2v p;
  p.x = (_Float16)a;
  p.y = (_Float16)b;
  wp[idx] = __builtin_bit_cast(uint32_t, p);
}

__global__ void prep_why(const float* __restrict__ why, _Float16* __restrict__ wt) {
  int idx = blockIdx.x * blockDim.x + threadIdx.x;   // 131072
  int v = idx >> 9;
  int k = idx & 511;
  wt[idx] = (_Float16)why[k * VOC + v];
}

// 4-col dot expansion for VGPR-held weight words
#define DOT4(W, H)                                         \
  a0 = fdot2f((W).x, (H), a0); a1 = fdot2f((W).y, (H), a1); \
  a2 = fdot2f((W).z, (H), a2); a3 = fdot2f((W).w, (H), a3);

// write 4 weight cols of one slice into hard-NAMED AGPRs (clobbered -> reserved)
#define AGWR4(A0, A1, A2, A3, V)                                   \
  asm volatile("v_accvgpr_write_b32 " A0 ", %0\n\t"                \
               "v_accvgpr_write_b32 " A1 ", %1\n\t"                \
               "v_accvgpr_write_b32 " A2 ", %2\n\t"                \
               "v_accvgpr_write_b32 " A3 ", %3"                    \
               :: "v"((V).x), "v"((V).y), "v"((V).z), "v"((V).w)   \
               : A0, A1, A2, A3)

// one read+dot pair; T = temp operand index string, ACC = acc operand index
#define AGP(A, ACC, T, H)                                  \
  "v_accvgpr_read_b32 " T ", " A "\n\t"                    \
  "v_dot2_f32_f16 " ACC ", " T ", " H ", " ACC "\n\t"

// one quad = 4 slices x 4 cols = 16 hard-named AGPRs vs one broadcast h-quad.
// %0-%3 accs, %4/%5 alternating temps, %6-%9 h words.
#define AGQUAD(A00,A01,A02,A03, A10,A11,A12,A13,                    \
               A20,A21,A22,A23, A30,A31,A32,A33, HQ)                \
  asm volatile(                                                     \
    AGP(A00,"%0","%4","%6") AGP(A01,"%1","%5","%6")                 \
    AGP(A02,"%2","%4","%6") AGP(A03,"%3","%5","%6")                 \
    AGP(A10,"%0","%4","%7") AGP(A11,"%1","%5","%7")                 \
    AGP(A12,"%2","%4","%7") AGP(A13,"%3","%5","%7")                 \
    AGP(A20,"%0","%4","%8") AGP(A21,"%1","%5","%8")                 \
    AGP(A22,"%2","%4","%8") AGP(A23,"%3","%5","%8")                 \
    AGP(A30,"%0","%4","%9") AGP(A31,"%1","%5","%9")                 \
    AGP(A32,"%2","%4","%9") AGP(A33,"%3","%5","%9")                 \
    : "+v"(a0), "+v"(a1), "+v"(a2), "+v"(a3), "=&v"(t0), "=&v"(t1)  \
    : "v"((HQ).x), "v"((HQ).y), "v"((HQ).z), "v"((HQ).w))

#define LOADW(S) (*((const uint4*)&wp[(size_t)(k2b + (S)) * HID + n0]))

// ---------------- phase 1: recurrence ----------------
// 64 blocks (one chain each), 512 threads = 8 waves, 1 block/CU.
// thread (kq=tid>>7, nb=tid&127): cols n0=nb*4..+3, slices [kq*64, kq*64+64).
// Residency: slices 0..31 hard-named AGPR a0..a127 (128 KB/CU, unspillable),
//            32..47 LDS (128 KB), 48..63 streamed L1 (128 KB/step).
__global__ __launch_bounds__(512, 2) void rnn_phase1(
    const int* __restrict__ x, const float* __restrict__ wih,
    const uint32_t* __restrict__ wp, const float* __restrict__ bh,
    __half* __restrict__ hbuf) {
  __shared__ __align__(16) uint32_t h2s[HID / 2];  // 1 KB
  __shared__ float part[4][HID];                   // 8 KB
  __shared__ int xtok[S_LEN];                      // 4 KB
  extern __shared__ __align__(16) uint4 lw[];      // 16*512 uint4 = 128 KB

  const int b   = blockIdx.x;
  const int tid = threadIdx.x;
  const int kq  = tid >> 7;
  const int nb  = tid & 127;
  const int n0  = nb * 4;
  const int k2b = kq * 64;

  // ---- one-time: slices 0..31 -> named AGPRs (a{4s+j} = col j of slice s)
  { uint4 v;
    v = LOADW(0);  AGWR4("a0","a1","a2","a3", v);
    v = LOADW(1);  AGWR4("a4","a5","a6","a7", v);
    v = LOADW(2);  AGWR4("a8","a9","a10","a11", v);
    v = LOADW(3);  AGWR4("a12","a13","a14","a15", v);
    v = LOADW(4);  AGWR4("a16","a17","a18","a19", v);
    v = LOADW(5);  AGWR4("a20","a21","a22","a23", v);
    v = LOADW(6);  AGWR4("a24","a25","a26","a27", v);
    v = LOADW(7);  AGWR4("a28","a29","a30","a31", v);
    v = LOADW(8);  AGWR4("a32","a33","a34","a35", v);
    v = LOADW(9);  AGWR4("a36","a37","a38","a39", v);
    v = LOADW(10); AGWR4("a40","a41","a42","a43", v);
    v = LOADW(11); AGWR4("a44","a45","a46","a47", v);
    v = LOADW(12); AGWR4("a48","a49","a50","a51", v);
    v = LOADW(13); AGWR4("a52","a53","a54","a55", v);
    v = LOADW(14); AGWR4("a56","a57","a58","a59", v);
    v = LOADW(15); AGWR4("a60","a61","a62","a63", v);
    v = LOADW(16); AGWR4("a64","a65","a66","a67", v);
    v = LOADW(17); AGWR4("a68","a69","a70","a71", v);
    v = LOADW(18); AGWR4("a72","a73","a74","a75", v);
    v = LOADW(19); AGWR4("a76","a77","a78","a79", v);
    v = LOADW(20); AGWR4("a80","a81","a82","a83", v);
    v = LOADW(21); AGWR4("a84","a85","a86","a87", v);
    v = LOADW(22); AGWR4("a88","a89","a90","a91", v);
    v = LOADW(23); AGWR4("a92","a93","a94","a95", v);
    v = LOADW(24); AGWR4("a96","a97","a98","a99", v);
    v = LOADW(25); AGWR4("a100","a101","a102","a103", v);
    v = LOADW(26); AGWR4("a104","a105","a106","a107", v);
    v = LOADW(27); AGWR4("a108","a109","a110","a111", v);
    v = LOADW(28); AGWR4("a112","a113","a114","a115", v);
    v = LOADW(29); AGWR4("a116","a117","a118","a119", v);
    v = LOADW(30); AGWR4("a120","a121","a122","a123", v);
    v = LOADW(31); AGWR4("a124","a125","a126","a127", v);
  }

  // ---- LDS-resident slices 32..47
#pragma unroll
  for (int si = 0; si < 16; ++si)
    lw[si * 512 + tid] = LOADW(32 + si);

  xtok[tid]       = x[b * S_LEN + tid];
  xtok[tid + 512] = x[b * S_LEN + tid + 512];
  if (tid < HID / 2) h2s[tid] = 0u;  // h0 = 0
  const float bh_r = bh[tid];
  __syncthreads();

  for (int t = 0; t < S_LEN; ++t) {
    const int tok = xtok[t];
    const float xe = wih[tok * HID + tid];  // early issue; used in reduce

    uint4 g[8];
#pragma unroll
    for (int i = 0; i < 8; ++i)  // stream batch 1 (slices 48..55)
      g[i] = LOADW(48 + i);

    float a0 = 0.f, a1 = 0.f, a2 = 0.f, a3 = 0.f;
    uint32_t t0, t1;
    const uint4* hq = (const uint4*)&h2s[k2b];  // wave-uniform broadcast reads

    // AGPR phase: slices 0..31
    AGQUAD("a0","a1","a2","a3","a4","a5","a6","a7",
           "a8","a9","a10","a11","a12","a13","a14","a15", hq[0]);
    AGQUAD("a16","a17","a18","a19","a20","a21","a22","a23",
           "a24","a25","a26","a27","a28","a29","a30","a31", hq[1]);
    AGQUAD("a32","a33","a34","a35","a36","a37","a38","a39",
           "a40","a41","a42","a43","a44","a45","a46","a47", hq[2]);
    AGQUAD("a48","a49","a50","a51","a52","a53","a54","a55",
           "a56","a57","a58","a59","a60","a61","a62","a63", hq[3]);
    AGQUAD("a64","a65","a66","a67","a68","a69","a70","a71",
           "a72","a73","a74","a75","a76","a77","a78","a79", hq[4]);
    AGQUAD("a80","a81","a82","a83","a84","a85","a86","a87",
           "a88","a89","a90","a91","a92","a93","a94","a95", hq[5]);
    AGQUAD("a96","a97","a98","a99","a100","a101","a102","a103",
           "a104","a105","a106","a107","a108","a109","a110","a111", hq[6]);
    AGQUAD("a112","a113","a114","a115","a116","a117","a118","a119",
           "a120","a121","a122","a123","a124","a125","a126","a127", hq[7]);

    // LDS phase: slices 32..47
#pragma unroll
    for (int q = 0; q < 4; ++q) {
      const uint4 hc = hq[8 + q];
      const uint4 l0 = lw[(q * 4 + 0) * 512 + tid];
      const uint4 l1 = lw[(q * 4 + 1) * 512 + tid];
      const uint4 l2 = lw[(q * 4 + 2) * 512 + tid];
      const uint4 l3 = lw[(q * 4 + 3) * 512 + tid];
      DOT4(l0, hc.x)
      DOT4(l1, hc.y)
      DOT4(l2, hc.z)
      DOT4(l3, hc.w)
    }

    // stream phase batch 1: slices 48..55
#pragma unroll
    for (int q = 0; q < 2; ++q) {
      const uint4 hc = hq[12 + q];
      DOT4(g[q * 4 + 0], hc.x)
      DOT4(g[q * 4 + 1], hc.y)
      DOT4(g[q * 4 + 2], hc.z)
      DOT4(g[q * 4 + 3], hc.w)
    }
    // stream batch 2 (slices 56..63), loads then dots
#pragma unroll
    for (int i = 0; i < 8; ++i)
      g[i] = LOADW(56 + i);
#pragma unroll
    for (int q = 0; q < 2; ++q) {
      const uint4 hc = hq[14 + q];
      DOT4(g[q * 4 + 0], hc.x)
      DOT4(g[q * 4 + 1], hc.y)
      DOT4(g[q * 4 + 2], hc.z)
      DOT4(g[q * 4 + 3], hc.w)
    }

    *((float4*)&part[kq][n0]) = make_float4(a0, a1, a2, a3);
    __syncthreads();  // B1: partials ready; all h2s reads of step t done

    {
      float s = part[0][tid] + part[1][tid] + part[2][tid] + part[3][tid];
      s += xe + bh_r;
      const float e = __builtin_amdgcn_exp2f(s * 2.885390081777927f);  // e^(2s)
      const float h = 1.0f - 2.0f * __builtin_amdgcn_rcpf(e + 1.0f);
      const __half hh = __float2half(h);
      hbuf[(size_t)(t * BATCH + b) * HID + tid] = hh;  // history for phase 2
      ((__half*)h2s)[tid] = hh;                         // recurrent state
    }
    __syncthreads();  // B2: new h visible before next step's reads
  }
}

// ---------------- phase 2: y = h @ W_hy + b_y (fp16 MFMA, in-place over d_out) ----
__global__ __launch_bounds__(256, 1) void rnn_phase2(
    void* __restrict__ out_, const _Float16* __restrict__ wt,
    const float* __restrict__ by) {
  const int tid = threadIdx.x;
  const int w = tid >> 6;
  const int l = tid & 63;
  const int la = l & 15;
  const int lb = l >> 4;
  const int rowbase = blockIdx.x * 64 + w * 16;

  const _Float16* hb = (const _Float16*)out_;
  float* out = (float*)out_;

  h8v a[16];
  const _Float16* arow = hb + (size_t)(rowbase + la) * HID + lb * 8;
#pragma unroll
  for (int kk = 0; kk < 16; ++kk)
    a[kk] = *((const h8v*)(arow + kk * 32));

#pragma unroll 1
  for (int cb = 0; cb < 16; ++cb) {
    f4v acc = {0.f, 0.f, 0.f, 0.f};
    const _Float16* brow = wt + (size_t)(cb * 16 + la) * HID + lb * 8;
#pragma unroll
    for (int kk = 0; kk < 16; ++kk) {
      const h8v bf = *((const h8v*)(brow + kk * 32));
      acc = __builtin_amdgcn_mfma_f32_16x16x32_f16(a[kk], bf, acc, 0, 0, 0);
    }
    const int col = cb * 16 + la;
    const float byv = by[col];
#pragma unroll
    for (int r = 0; r < 4; ++r) {
      const int row = rowbase + lb * 4 + r;  // C/D: col = lane&15, row = (lane>>4)*4 + r
      out[(size_t)row * VOC + col] = acc[r] + byv;
    }
  }
}

// ---------------- launch ----------------
extern "C" void kernel_launch(void* const* d_in, const int* in_sizes, int n_in,
                              void* d_out, int out_size, void* d_ws, size_t ws_size,
                              hipStream_t stream) {
  const int*   x   = (const int*)d_in[0];
  const float* wih = (const float*)d_in[1];
  const float* whh = (const float*)d_in[2];
  const float* bh  = (const float*)d_in[3];
  const float* why = (const float*)d_in[4];
  const float* by  = (const float*)d_in[5];

  uint32_t* wp = (uint32_t*)d_ws;                          // 512 KB packed fp16 W_hh
  _Float16* wt = (_Float16*)((char*)d_ws + 512 * 1024);    // 256 KB fp16 W_hy^T

  hipLaunchKernelGGL(prep_whh, dim3(512), dim3(256), 0, stream, whh, wp);
  hipLaunchKernelGGL(prep_why, dim3(512), dim3(256), 0, stream, why, wt);
  hipLaunchKernelGGL(rnn_phase1, dim3(BATCH), dim3(512), 131072, stream,
                     x, wih, wp, bh, (__half*)d_out);
  hipLaunchKernelGGL(rnn_phase2, dim3((S_LEN * BATCH) / 64), dim3(256), 0, stream,
                     d_out, wt, by);
}